// Round 7
// baseline (762.781 us; speedup 1.0000x reference)
//
#include <hip/hip_runtime.h>

#define NN 100000
#define NE 1600000
#define D 128
#define ODIM 40
#define CHUNK 16384
#define NBUCK 196      // ceil(NN/512)
#define BCAP 10240     // bucket capacity (mean 8192, sigma~90 -> +22 sigma)

typedef unsigned int uint;
typedef unsigned short ushort;

// bf16 helpers: h stored as bf16 pairs packed in uint; math fp32.
__device__ __forceinline__ uint pack_bf16x2(float lo, float hi) {
  uint ul = __float_as_uint(lo);
  uint uh = __float_as_uint(hi);
  ul = (ul + 0x7FFFu + ((ul >> 16) & 1u)) >> 16;   // RNE
  uh = (uh + 0x7FFFu + ((uh >> 16) & 1u)) >> 16;
  return ul | (uh << 16);
}
__device__ __forceinline__ float bf_lo(uint u) { return __uint_as_float(u << 16); }
__device__ __forceinline__ float bf_hi(uint u) { return __uint_as_float(u & 0xFFFF0000u); }

// ---------------- zero (bucketFill) ----------------
__global__ void k_zero(int* __restrict__ p, int n) {
  int i = blockIdx.x * blockDim.x + threadIdx.x;
  if (i < n) p[i] = 0;
}

// ---- pass A: bin edges into 196 fixed-capacity dst-bucket regions ----
// No offsets dependency: bucket b owns ebuf[b*BCAP .. b*BCAP+BCAP).
__global__ __launch_bounds__(256) void k_bin(const int* __restrict__ src,
    const int* __restrict__ dst, int* __restrict__ bucketFill, uint2* __restrict__ ebuf) {
  __shared__ int hist[NBUCK];
  __shared__ int hist2[NBUCK];
  __shared__ int gb[NBUCK];
  int tid = threadIdx.x;
  int base = blockIdx.x * CHUNK;
  int n = NE - base;
  if (n > CHUNK) n = CHUNK;
  for (int i = tid; i < NBUCK; i += 256) { hist[i] = 0; hist2[i] = 0; }
  __syncthreads();
  for (int i = tid; i < n; i += 256) {
    int d = dst[base + i];
    atomicAdd(&hist[d >> 9], 1);
  }
  __syncthreads();
  for (int i = tid; i < NBUCK; i += 256) {
    int cnt = hist[i];
    int off = (cnt > 0) ? atomicAdd(&bucketFill[i], cnt) : 0;
    gb[i] = i * BCAP + off;
  }
  __syncthreads();
  for (int i = tid; i < n; i += 256) {
    int s = src[base + i];
    int d = dst[base + i];
    int b = d >> 9;
    int lp = atomicAdd(&hist2[b], 1);
    int slot = gb[b] + lp;
    if (slot < (b + 1) * BCAP)            // overflow guard (statistically unreachable)
      ebuf[slot] = make_uint2((uint)s, (uint)d);
  }
}

// ---- pass B: per-bucket count + scan + CSR fill in LDS; writes csr/beg/end/dinv ----
__global__ __launch_bounds__(256) void k_fillb(const uint2* __restrict__ ebuf,
    const int* __restrict__ bucketFill, int* __restrict__ csr,
    int* __restrict__ beg, int* __restrict__ endv, float* __restrict__ dinv) {
  __shared__ int lfill[512];
  __shared__ int lfill2[512];
  __shared__ int loff[512];
  __shared__ int part[256];
  __shared__ int limage[BCAP];
  int tid = threadIdx.x;
  int b = blockIdx.x;
  int nb0 = b << 9;
  int nnodes = NN - nb0; if (nnodes > 512) nnodes = 512;
  int bn = bucketFill[b]; if (bn > BCAP) bn = BCAP;
  lfill[tid] = 0; lfill[tid + 256] = 0;
  lfill2[tid] = 0; lfill2[tid + 256] = 0;
  __syncthreads();
  const uint2* eb = ebuf + b * BCAP;
  for (int i = tid; i < bn; i += 256) atomicAdd(&lfill[(int)eb[i].y - nb0], 1);
  __syncthreads();
  // exclusive scan of 512 counts: pair-partials + Hillis-Steele over 256
  int v0 = lfill[2 * tid], v1 = lfill[2 * tid + 1];
  part[tid] = v0 + v1;
  __syncthreads();
  for (int off = 1; off < 256; off <<= 1) {
    int add = (tid >= off) ? part[tid - off] : 0;
    __syncthreads();
    part[tid] += add;
    __syncthreads();
  }
  int pex = part[tid] - (v0 + v1);
  loff[2 * tid] = pex;
  loff[2 * tid + 1] = pex + v0;
  __syncthreads();
  // per-node outputs
  for (int i = tid; i < nnodes; i += 256) {
    int cnt = lfill[i];
    dinv[nb0 + i] = rsqrtf((float)(cnt + 1));
    int bg = b * BCAP + loff[i];
    beg[nb0 + i] = bg;
    endv[nb0 + i] = bg + cnt;
  }
  // place into LDS image
  for (int i = tid; i < bn; i += 256) {
    uint2 p = eb[i];
    int dl = (int)p.y - nb0;
    int lp = atomicAdd(&lfill2[dl], 1);
    limage[loff[dl] + lp] = (int)p.x;
  }
  __syncthreads();
  // coalesced write-out
  for (int i = tid; i < bn; i += 256) csr[b * BCAP + i] = limage[i];
}

// ---- GEMM: H = bf16(dinv * (X @ W)), slice-major layout h[4][NN][32feats] ----
__global__ __launch_bounds__(256) void k_gemm128(const float* __restrict__ X,
    const float* __restrict__ W, const float* __restrict__ dinv, ushort* __restrict__ H) {
  __shared__ __align__(16) float At[32][64];    // A chunk, transposed: At[k][n]
  __shared__ __align__(16) float Wl[32][128];   // W chunk: Wl[k][f]
  int tid = threadIdx.x;
  int ft = tid & 15;   // feature group: features ft*8 .. ft*8+7
  int nt = tid >> 4;   // node group: nodes nt*4 .. nt*4+3
  int nbase = blockIdx.x * 64;
  float acc[4][8];
#pragma unroll
  for (int i = 0; i < 4; i++)
#pragma unroll
    for (int j = 0; j < 8; j++) acc[i][j] = 0.f;

  for (int k0 = 0; k0 < D; k0 += 32) {
    {  // stage A transposed: 64 nodes x 32 k
      int n = tid >> 2;
      int kv = (tid & 3) * 8;
      int gn = nbase + n;
      if (gn >= NN) gn = NN - 1;
      const float4* xp = (const float4*)&X[gn * D + k0 + kv];
      float4 a0 = xp[0];
      float4 a1 = xp[1];
      At[kv + 0][n] = a0.x; At[kv + 1][n] = a0.y; At[kv + 2][n] = a0.z; At[kv + 3][n] = a0.w;
      At[kv + 4][n] = a1.x; At[kv + 5][n] = a1.y; At[kv + 6][n] = a1.z; At[kv + 7][n] = a1.w;
    }
    {  // stage W chunk: 32 x 128
      int r = tid >> 5;
      int c = (tid & 31) * 4;
#pragma unroll
      for (int rr = 0; rr < 32; rr += 8)
        *(float4*)&Wl[r + rr][c] = *(const float4*)&W[(k0 + r + rr) * D + c];
    }
    __syncthreads();
#pragma unroll 8
    for (int k = 0; k < 32; k++) {
      float4 a  = *(float4*)&At[k][nt * 4];
      float4 w0 = *(float4*)&Wl[k][ft * 8];
      float4 w1 = *(float4*)&Wl[k][ft * 8 + 4];
      float av[4] = {a.x, a.y, a.z, a.w};
      float wv[8] = {w0.x, w0.y, w0.z, w0.w, w1.x, w1.y, w1.z, w1.w};
#pragma unroll
      for (int i = 0; i < 4; i++)
#pragma unroll
        for (int j = 0; j < 8; j++)
          acc[i][j] = fmaf(av[i], wv[j], acc[i][j]);
    }
    __syncthreads();
  }
  uint* hu = (uint*)H;
  int slice = ft >> 2;          // features ft*8..ft*8+7 lie in slice ft>>2
#pragma unroll
  for (int i = 0; i < 4; i++) {
    int gn = nbase + nt * 4 + i;
    if (gn < NN) {
      float di = dinv[gn];
      uint4 o;
      o.x = pack_bf16x2(acc[i][0] * di, acc[i][1] * di);
      o.y = pack_bf16x2(acc[i][2] * di, acc[i][3] * di);
      o.z = pack_bf16x2(acc[i][4] * di, acc[i][5] * di);
      o.w = pack_bf16x2(acc[i][6] * di, acc[i][7] * di);
      *(uint4*)&hu[slice * (NN * 16) + gn * 16 + (ft & 3) * 4] = o;
    }
  }
}

// ---- aggregate, XCD-sliced: slice = blockIdx&3 aligns with XCD round-robin ----
// wave = 1 node; 4 edge-groups x 16 feature-lanes; 64B line per edge-gather.
__global__ __launch_bounds__(256) void k_aggregate(const ushort* __restrict__ h,
    const int* __restrict__ csr, const int* __restrict__ beg, const int* __restrict__ endv,
    const float* __restrict__ dinv, const float* __restrict__ bias,
    float* __restrict__ out) {
  int bid = blockIdx.x;
  int slice = bid & 3;
  int tid = threadIdx.x;
  int node = (bid >> 2) * 4 + (tid >> 6);
  int lane = tid & 63;
  int g = lane >> 4;       // edge group 0..3
  int f = lane & 15;       // feature pair 0..15 (2 feats each)
  const uint* hv = (const uint*)h + slice * (NN * 16);
  int b_ = beg[node], e_ = endv[node];
  float ax0 = 0.f, ay0 = 0.f, ax1 = 0.f, ay1 = 0.f;
  for (int eb = b_; eb < e_; eb += 8) {
    int i0 = eb + g;
    int i1 = i0 + 4;
    if (i0 < e_) {
      int s = csr[i0];
      uint u = hv[s * 16 + f];
      ax0 += bf_lo(u); ay0 += bf_hi(u);
    }
    if (i1 < e_) {
      int s = csr[i1];
      uint u = hv[s * 16 + f];
      ax1 += bf_lo(u); ay1 += bf_hi(u);
    }
  }
  float ax = ax0 + ax1, ay = ay0 + ay1;
  ax += __shfl_xor(ax, 16); ay += __shfl_xor(ay, 16);
  ax += __shfl_xor(ax, 32); ay += __shfl_xor(ay, 32);
  uint us = hv[node * 16 + f];
  ax += bf_lo(us); ay += bf_hi(us);
  float di = dinv[node];
  float2 bv = *(const float2*)&bias[slice * 32 + f * 2];
  float o0 = fmaxf(fmaf(di, ax, bv.x), 0.f);
  float o1 = fmaxf(fmaf(di, ay, bv.y), 0.f);
  if (g == 0) {
    float2 o = {o0, o1};
    *(float2*)&out[node * D + slice * 32 + f * 2] = o;
  }
}

// ---------------- classifier: out[N,40] = X[N,128] @ Wc[128,40] + bc ----------------
__global__ __launch_bounds__(256) void k_classifier(const float* __restrict__ X,
    const float* __restrict__ Wc, const float* __restrict__ bc, float* __restrict__ out) {
  __shared__ __align__(16) float wl[D * ODIM];   // 20 KB
  __shared__ __align__(16) float xl[50 * D];     // 25 KB
  int tid = threadIdx.x;
  for (int i = tid; i < D * ODIM; i += 256) wl[i] = Wc[i];
  int nbase = blockIdx.x * 50;
  for (int i = tid; i < 50 * D; i += 256) {
    int gn = nbase + (i >> 7);
    xl[i] = (gn < NN) ? X[gn * D + (i & 127)] : 0.f;
  }
  __syncthreads();
  int fg = tid % 10;   // feature group of 4
  int np = tid / 10;   // node pair
  if (np < 25) {
    float acc0[4] = {0, 0, 0, 0};
    float acc1[4] = {0, 0, 0, 0};
    const float* x0 = &xl[(np * 2) * D];
    const float* x1 = &xl[(np * 2 + 1) * D];
#pragma unroll 4
    for (int k = 0; k < D; k++) {
      float4 w = *(float4*)&wl[k * ODIM + fg * 4];
      float xv0 = x0[k];
      float xv1 = x1[k];
      acc0[0] = fmaf(xv0, w.x, acc0[0]); acc0[1] = fmaf(xv0, w.y, acc0[1]);
      acc0[2] = fmaf(xv0, w.z, acc0[2]); acc0[3] = fmaf(xv0, w.w, acc0[3]);
      acc1[0] = fmaf(xv1, w.x, acc1[0]); acc1[1] = fmaf(xv1, w.y, acc1[1]);
      acc1[2] = fmaf(xv1, w.z, acc1[2]); acc1[3] = fmaf(xv1, w.w, acc1[3]);
    }
    float4 b = *(const float4*)&bc[fg * 4];
    int gn0 = nbase + np * 2;
    int gn1 = gn0 + 1;
    if (gn0 < NN) {
      float4 o = {acc0[0] + b.x, acc0[1] + b.y, acc0[2] + b.z, acc0[3] + b.w};
      *(float4*)&out[gn0 * ODIM + fg * 4] = o;
    }
    if (gn1 < NN) {
      float4 o = {acc1[0] + b.x, acc1[1] + b.y, acc1[2] + b.z, acc1[3] + b.w};
      *(float4*)&out[gn1 * ODIM + fg * 4] = o;
    }
  }
}

extern "C" void kernel_launch(void* const* d_in, const int* in_sizes, int n_in,
                              void* d_out, int out_size, void* d_ws, size_t ws_size,
                              hipStream_t stream) {
  const float* fts = (const float*)d_in[0];
  const int*   ei  = (const int*)d_in[1];
  const float* W1  = (const float*)d_in[2];
  const float* b1  = (const float*)d_in[3];
  const float* W2  = (const float*)d_in[4];
  const float* b2  = (const float*)d_in[5];
  const float* Wc  = (const float*)d_in[6];
  const float* bc  = (const float*)d_in[7];
  const int* src = ei;        // edge_index[0]
  const int* dst = ei + NE;   // edge_index[1]

  // workspace layout (16B-aligned offsets)
  char* ws = (char*)d_ws;
  int*    bucketFill = (int*)(ws + 0);              // 1024 B
  int*    beg        = (int*)(ws + 1024);           // 400000 B
  int*    endv       = (int*)(ws + 401024);         // 400000 B
  float*  dinv       = (float*)(ws + 801024);       // 400000 B
  int*    csr        = (int*)(ws + 1201024);        // 196*10240*4 = 8028160 B
  uint2*  ebuf       = (uint2*)(ws + 9229184);      // 196*10240*8 = 16056320 B
  ushort* h          = (ushort*)(ws + 25285504);    // 25600000 B (bf16, slice-major)
  // total ~50.9 MB

  float* outc = (float*)d_out;              // [N,40]
  float* x    = (float*)d_out + NN * ODIM;  // [N,128]  (x1 lives here, overwritten by x2)

  k_zero<<<1, 256, 0, stream>>>(bucketFill, NBUCK);
  k_bin<<<(NE + CHUNK - 1) / CHUNK, 256, 0, stream>>>(src, dst, bucketFill, ebuf);
  k_fillb<<<NBUCK, 256, 0, stream>>>(ebuf, bucketFill, csr, beg, endv, dinv);

  // layer 1: h = bf16(dinv * (fts @ W1)) ; x1 = relu(dinv*(sum+self) + b1)
  k_gemm128<<<(NN + 63) / 64, 256, 0, stream>>>(fts, W1, dinv, h);
  k_aggregate<<<NN, 256, 0, stream>>>(h, csr, beg, endv, dinv, b1, x);
  // layer 2
  k_gemm128<<<(NN + 63) / 64, 256, 0, stream>>>(x, W2, dinv, h);
  k_aggregate<<<NN, 256, 0, stream>>>(h, csr, beg, endv, dinv, b2, x);
  // classifier
  k_classifier<<<(NN + 49) / 50, 256, 0, stream>>>(x, Wc, bc, outc);
}

// Round 9
// 505.401 us; speedup vs baseline: 1.5093x; 1.5093x over previous
//
#include <hip/hip_runtime.h>

#define NN 100000
#define NE 1600000
#define D 128
#define ODIM 40
#define CHUNK 16384
#define NBUCK 196      // ceil(NN/512)
#define BCAP 10240     // bucket capacity (mean 8192, sigma~90 -> +22 sigma)

typedef unsigned int uint;
typedef unsigned short ushort;

// bf16 helpers: h stored as bf16 pairs packed in uint; math fp32.
__device__ __forceinline__ uint pack_bf16x2(float lo, float hi) {
  uint ul = __float_as_uint(lo);
  uint uh = __float_as_uint(hi);
  ul = (ul + 0x7FFFu + ((ul >> 16) & 1u)) >> 16;   // RNE
  uh = (uh + 0x7FFFu + ((uh >> 16) & 1u)) >> 16;
  return ul | (uh << 16);
}
__device__ __forceinline__ float bf_lo(uint u) { return __uint_as_float(u << 16); }
__device__ __forceinline__ float bf_hi(uint u) { return __uint_as_float(u & 0xFFFF0000u); }

// ---------------- zero (bucketFill) ----------------
__global__ void k_zero(int* __restrict__ p, int n) {
  int i = blockIdx.x * blockDim.x + threadIdx.x;
  if (i < n) p[i] = 0;
}

// ---- pass A: bin edges into 196 fixed-capacity dst-bucket regions ----
__global__ __launch_bounds__(256) void k_bin(const int* __restrict__ src,
    const int* __restrict__ dst, int* __restrict__ bucketFill, uint2* __restrict__ ebuf) {
  __shared__ int hist[NBUCK];
  __shared__ int hist2[NBUCK];
  __shared__ int gb[NBUCK];
  int tid = threadIdx.x;
  int base = blockIdx.x * CHUNK;
  int n = NE - base;
  if (n > CHUNK) n = CHUNK;
  for (int i = tid; i < NBUCK; i += 256) { hist[i] = 0; hist2[i] = 0; }
  __syncthreads();
  for (int i = tid; i < n; i += 256) {
    int d = dst[base + i];
    atomicAdd(&hist[d >> 9], 1);
  }
  __syncthreads();
  for (int i = tid; i < NBUCK; i += 256) {
    int cnt = hist[i];
    int off = (cnt > 0) ? atomicAdd(&bucketFill[i], cnt) : 0;
    gb[i] = i * BCAP + off;
  }
  __syncthreads();
  for (int i = tid; i < n; i += 256) {
    int s = src[base + i];
    int d = dst[base + i];
    int b = d >> 9;
    int lp = atomicAdd(&hist2[b], 1);
    int slot = gb[b] + lp;
    if (slot < (b + 1) * BCAP)            // overflow guard (statistically unreachable)
      ebuf[slot] = make_uint2((uint)s, (uint)d);
  }
}

// ---- pass B: per-bucket count + scan + CSR fill in LDS; writes csr/beg/end/dinv ----
__global__ __launch_bounds__(256) void k_fillb(const uint2* __restrict__ ebuf,
    const int* __restrict__ bucketFill, int* __restrict__ csr,
    int* __restrict__ beg, int* __restrict__ endv, float* __restrict__ dinv) {
  __shared__ int lfill[512];
  __shared__ int lfill2[512];
  __shared__ int loff[512];
  __shared__ int part[256];
  __shared__ int limage[BCAP];
  int tid = threadIdx.x;
  int b = blockIdx.x;
  int nb0 = b << 9;
  int nnodes = NN - nb0; if (nnodes > 512) nnodes = 512;
  int bn = bucketFill[b]; if (bn > BCAP) bn = BCAP;
  lfill[tid] = 0; lfill[tid + 256] = 0;
  lfill2[tid] = 0; lfill2[tid + 256] = 0;
  __syncthreads();
  const uint2* eb = ebuf + b * BCAP;
  for (int i = tid; i < bn; i += 256) atomicAdd(&lfill[(int)eb[i].y - nb0], 1);
  __syncthreads();
  // exclusive scan of 512 counts: pair-partials + Hillis-Steele over 256
  int v0 = lfill[2 * tid], v1 = lfill[2 * tid + 1];
  part[tid] = v0 + v1;
  __syncthreads();
  for (int off = 1; off < 256; off <<= 1) {
    int add = (tid >= off) ? part[tid - off] : 0;
    __syncthreads();
    part[tid] += add;
    __syncthreads();
  }
  int pex = part[tid] - (v0 + v1);
  loff[2 * tid] = pex;
  loff[2 * tid + 1] = pex + v0;
  __syncthreads();
  // per-node outputs
  for (int i = tid; i < nnodes; i += 256) {
    int cnt = lfill[i];
    dinv[nb0 + i] = rsqrtf((float)(cnt + 1));
    int bg = b * BCAP + loff[i];
    beg[nb0 + i] = bg;
    endv[nb0 + i] = bg + cnt;
  }
  // place into LDS image
  for (int i = tid; i < bn; i += 256) {
    uint2 p = eb[i];
    int dl = (int)p.y - nb0;
    int lp = atomicAdd(&lfill2[dl], 1);
    limage[loff[dl] + lp] = (int)p.x;
  }
  __syncthreads();
  // coalesced write-out
  for (int i = tid; i < bn; i += 256) csr[b * BCAP + i] = limage[i];
}

// ---- GEMM: H[N,128] = bf16( dinv[n] * (X[N,128] @ W[128,128]) ), row-major ----
__global__ __launch_bounds__(256) void k_gemm128(const float* __restrict__ X,
    const float* __restrict__ W, const float* __restrict__ dinv, ushort* __restrict__ H) {
  __shared__ __align__(16) float At[32][64];    // A chunk, transposed: At[k][n]
  __shared__ __align__(16) float Wl[32][128];   // W chunk: Wl[k][f]
  int tid = threadIdx.x;
  int ft = tid & 15;   // feature group: features ft*8 .. ft*8+7
  int nt = tid >> 4;   // node group: nodes nt*4 .. nt*4+3
  int nbase = blockIdx.x * 64;
  float acc[4][8];
#pragma unroll
  for (int i = 0; i < 4; i++)
#pragma unroll
    for (int j = 0; j < 8; j++) acc[i][j] = 0.f;

  for (int k0 = 0; k0 < D; k0 += 32) {
    {  // stage A transposed: 64 nodes x 32 k
      int n = tid >> 2;
      int kv = (tid & 3) * 8;
      int gn = nbase + n;
      if (gn >= NN) gn = NN - 1;
      const float4* xp = (const float4*)&X[gn * D + k0 + kv];
      float4 a0 = xp[0];
      float4 a1 = xp[1];
      At[kv + 0][n] = a0.x; At[kv + 1][n] = a0.y; At[kv + 2][n] = a0.z; At[kv + 3][n] = a0.w;
      At[kv + 4][n] = a1.x; At[kv + 5][n] = a1.y; At[kv + 6][n] = a1.z; At[kv + 7][n] = a1.w;
    }
    {  // stage W chunk: 32 x 128
      int r = tid >> 5;
      int c = (tid & 31) * 4;
#pragma unroll
      for (int rr = 0; rr < 32; rr += 8)
        *(float4*)&Wl[r + rr][c] = *(const float4*)&W[(k0 + r + rr) * D + c];
    }
    __syncthreads();
#pragma unroll 8
    for (int k = 0; k < 32; k++) {
      float4 a  = *(float4*)&At[k][nt * 4];
      float4 w0 = *(float4*)&Wl[k][ft * 8];
      float4 w1 = *(float4*)&Wl[k][ft * 8 + 4];
      float av[4] = {a.x, a.y, a.z, a.w};
      float wv[8] = {w0.x, w0.y, w0.z, w0.w, w1.x, w1.y, w1.z, w1.w};
#pragma unroll
      for (int i = 0; i < 4; i++)
#pragma unroll
        for (int j = 0; j < 8; j++)
          acc[i][j] = fmaf(av[i], wv[j], acc[i][j]);
    }
    __syncthreads();
  }
#pragma unroll
  for (int i = 0; i < 4; i++) {
    int gn = nbase + nt * 4 + i;
    if (gn < NN) {
      float di = dinv[gn];
      uint4 o;
      o.x = pack_bf16x2(acc[i][0] * di, acc[i][1] * di);
      o.y = pack_bf16x2(acc[i][2] * di, acc[i][3] * di);
      o.z = pack_bf16x2(acc[i][4] * di, acc[i][5] * di);
      o.w = pack_bf16x2(acc[i][6] * di, acc[i][7] * di);
      *(uint4*)&H[gn * D + ft * 8] = o;   // 16B aligned
    }
  }
}

// ---- aggregate: x = relu( dinv[i] * (Sum h'[s] + h'[i]) + b ), h' = dinv*h in bf16 ----
// wave = 1 node full row (64 uints = 128 feats); 4-edge unroll for MLP.
__global__ __launch_bounds__(256) void k_aggregate(const ushort* __restrict__ h,
    const int* __restrict__ csr, const int* __restrict__ beg, const int* __restrict__ endv,
    const float* __restrict__ dinv, const float* __restrict__ bias,
    float* __restrict__ out) {
  int node = blockIdx.x * 4 + (threadIdx.x >> 6);
  int lane = threadIdx.x & 63;
  if (node >= NN) return;
  int e = beg[node];
  int end = endv[node];
  const uint* hv = (const uint*)h;   // one uint = 2 bf16 features; row = 64 uints
  float a0x = 0.f, a0y = 0.f, a1x = 0.f, a1y = 0.f;
  float a2x = 0.f, a2y = 0.f, a3x = 0.f, a3y = 0.f;
  for (; e + 3 < end; e += 4) {
    int s0 = csr[e], s1 = csr[e + 1], s2 = csr[e + 2], s3 = csr[e + 3];
    uint u0 = hv[s0 * 64 + lane];
    uint u1 = hv[s1 * 64 + lane];
    uint u2 = hv[s2 * 64 + lane];
    uint u3 = hv[s3 * 64 + lane];
    a0x += bf_lo(u0); a0y += bf_hi(u0);
    a1x += bf_lo(u1); a1y += bf_hi(u1);
    a2x += bf_lo(u2); a2y += bf_hi(u2);
    a3x += bf_lo(u3); a3y += bf_hi(u3);
  }
  for (; e < end; e++) {
    int s0 = csr[e];
    uint u0 = hv[s0 * 64 + lane];
    a0x += bf_lo(u0); a0y += bf_hi(u0);
  }
  float di = dinv[node];
  uint us = hv[node * 64 + lane];
  float2 b = *(const float2*)&bias[lane * 2];
  float sx = (a0x + a1x) + (a2x + a3x) + bf_lo(us);
  float sy = (a0y + a1y) + (a2y + a3y) + bf_hi(us);
  float o0 = fmaxf(fmaf(di, sx, b.x), 0.f);
  float o1 = fmaxf(fmaf(di, sy, b.y), 0.f);
  float2 o = {o0, o1};
  *(float2*)&out[node * D + lane * 2] = o;
}

// ---------------- classifier: out[N,40] = X[N,128] @ Wc[128,40] + bc ----------------
__global__ __launch_bounds__(256) void k_classifier(const float* __restrict__ X,
    const float* __restrict__ Wc, const float* __restrict__ bc, float* __restrict__ out) {
  __shared__ __align__(16) float wl[D * ODIM];   // 20 KB
  __shared__ __align__(16) float xl[50 * D];     // 25 KB
  int tid = threadIdx.x;
  for (int i = tid; i < D * ODIM; i += 256) wl[i] = Wc[i];
  int nbase = blockIdx.x * 50;
  for (int i = tid; i < 50 * D; i += 256) {
    int gn = nbase + (i >> 7);
    xl[i] = (gn < NN) ? X[gn * D + (i & 127)] : 0.f;
  }
  __syncthreads();
  int fg = tid % 10;   // feature group of 4
  int np = tid / 10;   // node pair
  if (np < 25) {
    float acc0[4] = {0, 0, 0, 0};
    float acc1[4] = {0, 0, 0, 0};
    const float* x0 = &xl[(np * 2) * D];
    const float* x1 = &xl[(np * 2 + 1) * D];
#pragma unroll 4
    for (int k = 0; k < D; k++) {
      float4 w = *(float4*)&wl[k * ODIM + fg * 4];
      float xv0 = x0[k];
      float xv1 = x1[k];
      acc0[0] = fmaf(xv0, w.x, acc0[0]); acc0[1] = fmaf(xv0, w.y, acc0[1]);
      acc0[2] = fmaf(xv0, w.z, acc0[2]); acc0[3] = fmaf(xv0, w.w, acc0[3]);
      acc1[0] = fmaf(xv1, w.x, acc1[0]); acc1[1] = fmaf(xv1, w.y, acc1[1]);
      acc1[2] = fmaf(xv1, w.z, acc1[2]); acc1[3] = fmaf(xv1, w.w, acc1[3]);
    }
    float4 b = *(const float4*)&bc[fg * 4];
    int gn0 = nbase + np * 2;
    int gn1 = gn0 + 1;
    if (gn0 < NN) {
      float4 o = {acc0[0] + b.x, acc0[1] + b.y, acc0[2] + b.z, acc0[3] + b.w};
      *(float4*)&out[gn0 * ODIM + fg * 4] = o;
    }
    if (gn1 < NN) {
      float4 o = {acc1[0] + b.x, acc1[1] + b.y, acc1[2] + b.z, acc1[3] + b.w};
      *(float4*)&out[gn1 * ODIM + fg * 4] = o;
    }
  }
}

extern "C" void kernel_launch(void* const* d_in, const int* in_sizes, int n_in,
                              void* d_out, int out_size, void* d_ws, size_t ws_size,
                              hipStream_t stream) {
  const float* fts = (const float*)d_in[0];
  const int*   ei  = (const int*)d_in[1];
  const float* W1  = (const float*)d_in[2];
  const float* b1  = (const float*)d_in[3];
  const float* W2  = (const float*)d_in[4];
  const float* b2  = (const float*)d_in[5];
  const float* Wc  = (const float*)d_in[6];
  const float* bc  = (const float*)d_in[7];
  const int* src = ei;        // edge_index[0]
  const int* dst = ei + NE;   // edge_index[1]

  // workspace layout (16B-aligned offsets)
  char* ws = (char*)d_ws;
  int*    bucketFill = (int*)(ws + 0);              // 1024 B
  int*    beg        = (int*)(ws + 1024);           // 400000 B
  int*    endv       = (int*)(ws + 401024);         // 400000 B
  float*  dinv       = (float*)(ws + 801024);       // 400000 B
  int*    csr        = (int*)(ws + 1201024);        // 196*10240*4 = 8028160 B
  uint2*  ebuf       = (uint2*)(ws + 9229184);      // 196*10240*8 = 16056320 B
  ushort* h          = (ushort*)(ws + 25285504);    // 25600000 B (bf16, row-major)
  // total ~50.9 MB

  float* outc = (float*)d_out;              // [N,40]
  float* x    = (float*)d_out + NN * ODIM;  // [N,128]  (x1 lives here, overwritten by x2)

  k_zero<<<1, 256, 0, stream>>>(bucketFill, NBUCK);
  k_bin<<<(NE + CHUNK - 1) / CHUNK, 256, 0, stream>>>(src, dst, bucketFill, ebuf);
  k_fillb<<<NBUCK, 256, 0, stream>>>(ebuf, bucketFill, csr, beg, endv, dinv);

  // layer 1: h = bf16(dinv * (fts @ W1)) ; x1 = relu(dinv*(sum+self) + b1)
  k_gemm128<<<(NN + 63) / 64, 256, 0, stream>>>(fts, W1, dinv, h);
  k_aggregate<<<(NN + 3) / 4, 256, 0, stream>>>(h, csr, beg, endv, dinv, b1, x);
  // layer 2
  k_gemm128<<<(NN + 63) / 64, 256, 0, stream>>>(x, W2, dinv, h);
  k_aggregate<<<(NN + 3) / 4, 256, 0, stream>>>(h, csr, beg, endv, dinv, b2, x);
  // classifier
  k_classifier<<<(NN + 49) / 50, 256, 0, stream>>>(x, Wc, bc, outc);
}

// Round 11
// 432.244 us; speedup vs baseline: 1.7647x; 1.1692x over previous
//
#include <hip/hip_runtime.h>

#define NN 100000
#define NE 1600000
#define D 128
#define ODIM 40
#define CHUNK 16384
#define NBUCK 196      // ceil(NN/512)
#define BCAP 10240     // bucket capacity (mean 8192, sigma~90 -> +22 sigma)

typedef unsigned int uint;
typedef unsigned short ushort;
typedef __attribute__((ext_vector_type(8))) short short8v;   // 8 bf16 = 4 VGPR MFMA frag
typedef __attribute__((ext_vector_type(4))) float f32x4;     // MFMA accumulator

// bf16 helpers (RNE)
__device__ __forceinline__ ushort bf16_rne(float x) {
  uint u = __float_as_uint(x);
  u = (u + 0x7FFFu + ((u >> 16) & 1u)) >> 16;
  return (ushort)u;
}
__device__ __forceinline__ uint pack_bf16x2(float lo, float hi) {
  return (uint)bf16_rne(lo) | ((uint)bf16_rne(hi) << 16);
}
__device__ __forceinline__ float bf_lo(uint u) { return __uint_as_float(u << 16); }
__device__ __forceinline__ float bf_hi(uint u) { return __uint_as_float(u & 0xFFFF0000u); }

// ---------------- zero (bucketFill) ----------------
__global__ void k_zero(int* __restrict__ p, int n) {
  int i = blockIdx.x * blockDim.x + threadIdx.x;
  if (i < n) p[i] = 0;
}

// ---- pass A: bin edges into 196 fixed-capacity dst-bucket regions ----
__global__ __launch_bounds__(256) void k_bin(const int* __restrict__ src,
    const int* __restrict__ dst, int* __restrict__ bucketFill, uint2* __restrict__ ebuf) {
  __shared__ int hist[NBUCK];
  __shared__ int hist2[NBUCK];
  __shared__ int gb[NBUCK];
  int tid = threadIdx.x;
  int base = blockIdx.x * CHUNK;
  int n = NE - base;
  if (n > CHUNK) n = CHUNK;
  for (int i = tid; i < NBUCK; i += 256) { hist[i] = 0; hist2[i] = 0; }
  __syncthreads();
  for (int i = tid; i < n; i += 256) {
    int d = dst[base + i];
    atomicAdd(&hist[d >> 9], 1);
  }
  __syncthreads();
  for (int i = tid; i < NBUCK; i += 256) {
    int cnt = hist[i];
    int off = (cnt > 0) ? atomicAdd(&bucketFill[i], cnt) : 0;
    gb[i] = i * BCAP + off;
  }
  __syncthreads();
  for (int i = tid; i < n; i += 256) {
    int s = src[base + i];
    int d = dst[base + i];
    int b = d >> 9;
    int lp = atomicAdd(&hist2[b], 1);
    int slot = gb[b] + lp;
    if (slot < (b + 1) * BCAP)            // overflow guard (statistically unreachable)
      ebuf[slot] = make_uint2((uint)s, (uint)d);
  }
}

// ---- pass B: per-bucket count + scan + CSR fill in LDS; writes csr/beg/end/dinv ----
__global__ __launch_bounds__(256) void k_fillb(const uint2* __restrict__ ebuf,
    const int* __restrict__ bucketFill, int* __restrict__ csr,
    int* __restrict__ beg, int* __restrict__ endv, float* __restrict__ dinv) {
  __shared__ int lfill[512];
  __shared__ int lfill2[512];
  __shared__ int loff[512];
  __shared__ int part[256];
  __shared__ int limage[BCAP];
  int tid = threadIdx.x;
  int b = blockIdx.x;
  int nb0 = b << 9;
  int nnodes = NN - nb0; if (nnodes > 512) nnodes = 512;
  int bn = bucketFill[b]; if (bn > BCAP) bn = BCAP;
  lfill[tid] = 0; lfill[tid + 256] = 0;
  lfill2[tid] = 0; lfill2[tid + 256] = 0;
  __syncthreads();
  const uint2* eb = ebuf + b * BCAP;
  for (int i = tid; i < bn; i += 256) atomicAdd(&lfill[(int)eb[i].y - nb0], 1);
  __syncthreads();
  // exclusive scan of 512 counts: pair-partials + Hillis-Steele over 256
  int v0 = lfill[2 * tid], v1 = lfill[2 * tid + 1];
  part[tid] = v0 + v1;
  __syncthreads();
  for (int off = 1; off < 256; off <<= 1) {
    int add = (tid >= off) ? part[tid - off] : 0;
    __syncthreads();
    part[tid] += add;
    __syncthreads();
  }
  int pex = part[tid] - (v0 + v1);
  loff[2 * tid] = pex;
  loff[2 * tid + 1] = pex + v0;
  __syncthreads();
  // per-node outputs
  for (int i = tid; i < nnodes; i += 256) {
    int cnt = lfill[i];
    dinv[nb0 + i] = rsqrtf((float)(cnt + 1));
    int bg = b * BCAP + loff[i];
    beg[nb0 + i] = bg;
    endv[nb0 + i] = bg + cnt;
  }
  // place into LDS image
  for (int i = tid; i < bn; i += 256) {
    uint2 p = eb[i];
    int dl = (int)p.y - nb0;
    int lp = atomicAdd(&lfill2[dl], 1);
    limage[loff[dl] + lp] = (int)p.x;
  }
  __syncthreads();
  // coalesced write-out
  for (int i = tid; i < bn; i += 256) csr[b * BCAP + i] = limage[i];
}

// ---- MFMA GEMM: H[N,128] = bf16( dinv[n] * (X[N,128] @ W[128,128]) ) ----
// Block: 64 nodes x 128 feats, 4 waves; wave w owns nodes w*16..w*16+15.
// A-frag: lane(l&15)=node row, 8 contiguous k. B-frag from Wt[f][k]: lane(l&15)=feat col.
// C/D (m89-verified): col=lane&15, row=(lane>>4)*4+reg.
__global__ __launch_bounds__(256) void k_gemm_mfma(const float* __restrict__ X,
    const float* __restrict__ W, const float* __restrict__ dinv, ushort* __restrict__ H) {
  __shared__ __align__(16) ushort Xb[64][136];   // 272B row = 4-bank shift (conflict floor)
  __shared__ __align__(16) ushort Wt[128][136];  // W transposed [feat][k]
  __shared__ float ddi[64];
  int tid = threadIdx.x;
  int nbase = blockIdx.x * 64;
  // stage X -> bf16 (coalesced global read, contiguous LDS u16 write)
  for (int i = tid; i < 64 * 128; i += 256) {
    int n = i >> 7, k = i & 127;
    int gn = nbase + n; if (gn >= NN) gn = NN - 1;
    Xb[n][k] = bf16_rne(X[gn * D + k]);
  }
  // stage W transposed (coalesced global read; one-time strided u16 LDS write)
  for (int i = tid; i < 128 * 128; i += 256) {
    int k = i >> 7, f = i & 127;
    Wt[f][k] = bf16_rne(W[i]);
  }
  if (tid < 64) {
    int gn = nbase + tid; if (gn >= NN) gn = NN - 1;
    ddi[tid] = dinv[gn];
  }
  __syncthreads();
  int w = tid >> 6, l = tid & 63;
  int lr = l & 15, lg = l >> 4;
  int n0 = w * 16;
  f32x4 acc[8];
#pragma unroll
  for (int t = 0; t < 8; t++) acc[t] = (f32x4){0.f, 0.f, 0.f, 0.f};
#pragma unroll
  for (int k0 = 0; k0 < 128; k0 += 32) {
    short8v a = *(const short8v*)&Xb[n0 + lr][k0 + lg * 8];
#pragma unroll
    for (int ft = 0; ft < 8; ft++) {
      short8v b = *(const short8v*)&Wt[ft * 16 + lr][k0 + lg * 8];
      acc[ft] = __builtin_amdgcn_mfma_f32_16x16x32_bf16(a, b, acc[ft], 0, 0, 0);
    }
  }
  // epilogue: lane holds D[n0+lg*4+j][ft*16+lr]; scale by dinv, pack bf16
#pragma unroll
  for (int j = 0; j < 4; j++) {
    int nl = n0 + lg * 4 + j;
    int gn = nbase + nl;
    if (gn < NN) {
      float di = ddi[nl];
#pragma unroll
      for (int ft = 0; ft < 8; ft++) {
        H[gn * D + ft * 16 + lr] = bf16_rne(acc[ft][j] * di);
      }
    }
  }
}

// ---- aggregate: x = relu( dinv[i] * (Sum h'[s] + h'[i]) + b ), h' = dinv*h in bf16 ----
// wave = 1 node full row; 8-edge unroll for latency hiding (8 gathers in flight).
__global__ __launch_bounds__(256) void k_aggregate(const ushort* __restrict__ h,
    const int* __restrict__ csr, const int* __restrict__ beg, const int* __restrict__ endv,
    const float* __restrict__ dinv, const float* __restrict__ bias,
    float* __restrict__ out) {
  int node = blockIdx.x * 4 + (threadIdx.x >> 6);
  int lane = threadIdx.x & 63;
  if (node >= NN) return;
  int e = beg[node];
  int end = endv[node];
  const uint* hv = (const uint*)h;   // one uint = 2 bf16 features; row = 64 uints
  float ax0 = 0.f, ax1 = 0.f, ax2 = 0.f, ax3 = 0.f;
  float ax4 = 0.f, ax5 = 0.f, ax6 = 0.f, ax7 = 0.f;
  float ay0 = 0.f, ay1 = 0.f, ay2 = 0.f, ay3 = 0.f;
  float ay4 = 0.f, ay5 = 0.f, ay6 = 0.f, ay7 = 0.f;
  for (; e + 7 < end; e += 8) {
    int s0 = csr[e],     s1 = csr[e + 1], s2 = csr[e + 2], s3 = csr[e + 3];
    int s4 = csr[e + 4], s5 = csr[e + 5], s6 = csr[e + 6], s7 = csr[e + 7];
    uint u0 = hv[s0 * 64 + lane];
    uint u1 = hv[s1 * 64 + lane];
    uint u2 = hv[s2 * 64 + lane];
    uint u3 = hv[s3 * 64 + lane];
    uint u4 = hv[s4 * 64 + lane];
    uint u5 = hv[s5 * 64 + lane];
    uint u6 = hv[s6 * 64 + lane];
    uint u7 = hv[s7 * 64 + lane];
    ax0 += bf_lo(u0); ay0 += bf_hi(u0);
    ax1 += bf_lo(u1); ay1 += bf_hi(u1);
    ax2 += bf_lo(u2); ay2 += bf_hi(u2);
    ax3 += bf_lo(u3); ay3 += bf_hi(u3);
    ax4 += bf_lo(u4); ay4 += bf_hi(u4);
    ax5 += bf_lo(u5); ay5 += bf_hi(u5);
    ax6 += bf_lo(u6); ay6 += bf_hi(u6);
    ax7 += bf_lo(u7); ay7 += bf_hi(u7);
  }
  for (; e + 3 < end; e += 4) {
    int s0 = csr[e], s1 = csr[e + 1], s2 = csr[e + 2], s3 = csr[e + 3];
    uint u0 = hv[s0 * 64 + lane];
    uint u1 = hv[s1 * 64 + lane];
    uint u2 = hv[s2 * 64 + lane];
    uint u3 = hv[s3 * 64 + lane];
    ax0 += bf_lo(u0); ay0 += bf_hi(u0);
    ax1 += bf_lo(u1); ay1 += bf_hi(u1);
    ax2 += bf_lo(u2); ay2 += bf_hi(u2);
    ax3 += bf_lo(u3); ay3 += bf_hi(u3);
  }
  for (; e < end; e++) {
    int s0 = csr[e];
    uint u0 = hv[s0 * 64 + lane];
    ax0 += bf_lo(u0); ay0 += bf_hi(u0);
  }
  float di = dinv[node];
  uint us = hv[node * 64 + lane];
  float2 b = *(const float2*)&bias[lane * 2];
  float sx = ((ax0 + ax1) + (ax2 + ax3)) + ((ax4 + ax5) + (ax6 + ax7)) + bf_lo(us);
  float sy = ((ay0 + ay1) + (ay2 + ay3)) + ((ay4 + ay5) + (ay6 + ay7)) + bf_hi(us);
  float o0 = fmaxf(fmaf(di, sx, b.x), 0.f);
  float o1 = fmaxf(fmaf(di, sy, b.y), 0.f);
  float2 o = {o0, o1};
  *(float2*)&out[node * D + lane * 2] = o;
}

// ---------------- classifier: out[N,40] = X[N,128] @ Wc[128,40] + bc ----------------
__global__ __launch_bounds__(256) void k_classifier(const float* __restrict__ X,
    const float* __restrict__ Wc, const float* __restrict__ bc, float* __restrict__ out) {
  __shared__ __align__(16) float wl[D * ODIM];   // 20 KB
  __shared__ __align__(16) float xl[50 * D];     // 25 KB
  int tid = threadIdx.x;
  for (int i = tid; i < D * ODIM; i += 256) wl[i] = Wc[i];
  int nbase = blockIdx.x * 50;
  for (int i = tid; i < 50 * D; i += 256) {
    int gn = nbase + (i >> 7);
    xl[i] = (gn < NN) ? X[gn * D + (i & 127)] : 0.f;
  }
  __syncthreads();
  int fg = tid % 10;   // feature group of 4
  int np = tid / 10;   // node pair
  if (np < 25) {
    float acc0[4] = {0, 0, 0, 0};
    float acc1[4] = {0, 0, 0, 0};
    const float* x0 = &xl[(np * 2) * D];
    const float* x1 = &xl[(np * 2 + 1) * D];
#pragma unroll 4
    for (int k = 0; k < D; k++) {
      float4 w = *(float4*)&wl[k * ODIM + fg * 4];
      float xv0 = x0[k];
      float xv1 = x1[k];
      acc0[0] = fmaf(xv0, w.x, acc0[0]); acc0[1] = fmaf(xv0, w.y, acc0[1]);
      acc0[2] = fmaf(xv0, w.z, acc0[2]); acc0[3] = fmaf(xv0, w.w, acc0[3]);
      acc1[0] = fmaf(xv1, w.x, acc1[0]); acc1[1] = fmaf(xv1, w.y, acc1[1]);
      acc1[2] = fmaf(xv1, w.z, acc1[2]); acc1[3] = fmaf(xv1, w.w, acc1[3]);
    }
    float4 b = *(const float4*)&bc[fg * 4];
    int gn0 = nbase + np * 2;
    int gn1 = gn0 + 1;
    if (gn0 < NN) {
      float4 o = {acc0[0] + b.x, acc0[1] + b.y, acc0[2] + b.z, acc0[3] + b.w};
      *(float4*)&out[gn0 * ODIM + fg * 4] = o;
    }
    if (gn1 < NN) {
      float4 o = {acc1[0] + b.x, acc1[1] + b.y, acc1[2] + b.z, acc1[3] + b.w};
      *(float4*)&out[gn1 * ODIM + fg * 4] = o;
    }
  }
}

extern "C" void kernel_launch(void* const* d_in, const int* in_sizes, int n_in,
                              void* d_out, int out_size, void* d_ws, size_t ws_size,
                              hipStream_t stream) {
  const float* fts = (const float*)d_in[0];
  const int*   ei  = (const int*)d_in[1];
  const float* W1  = (const float*)d_in[2];
  const float* b1  = (const float*)d_in[3];
  const float* W2  = (const float*)d_in[4];
  const float* b2  = (const float*)d_in[5];
  const float* Wc  = (const float*)d_in[6];
  const float* bc  = (const float*)d_in[7];
  const int* src = ei;        // edge_index[0]
  const int* dst = ei + NE;   // edge_index[1]

  // workspace layout (16B-aligned offsets)
  char* ws = (char*)d_ws;
  int*    bucketFill = (int*)(ws + 0);              // 1024 B
  int*    beg        = (int*)(ws + 1024);           // 400000 B
  int*    endv       = (int*)(ws + 401024);         // 400000 B
  float*  dinv       = (float*)(ws + 801024);       // 400000 B
  int*    csr        = (int*)(ws + 1201024);        // 196*10240*4 = 8028160 B
  uint2*  ebuf       = (uint2*)(ws + 9229184);      // 196*10240*8 = 16056320 B
  ushort* h          = (ushort*)(ws + 25285504);    // 25600000 B (bf16, row-major)
  // total ~50.9 MB

  float* outc = (float*)d_out;              // [N,40]
  float* x    = (float*)d_out + NN * ODIM;  // [N,128]  (x1 lives here, overwritten by x2)

  k_zero<<<1, 256, 0, stream>>>(bucketFill, NBUCK);
  k_bin<<<(NE + CHUNK - 1) / CHUNK, 256, 0, stream>>>(src, dst, bucketFill, ebuf);
  k_fillb<<<NBUCK, 256, 0, stream>>>(ebuf, bucketFill, csr, beg, endv, dinv);

  // layer 1: h = bf16(dinv * (fts @ W1)) ; x1 = relu(dinv*(sum+self) + b1)
  k_gemm_mfma<<<(NN + 63) / 64, 256, 0, stream>>>(fts, W1, dinv, h);
  k_aggregate<<<(NN + 3) / 4, 256, 0, stream>>>(h, csr, beg, endv, dinv, b1, x);
  // layer 2
  k_gemm_mfma<<<(NN + 63) / 64, 256, 0, stream>>>(x, W2, dinv, h);
  k_aggregate<<<(NN + 3) / 4, 256, 0, stream>>>(h, csr, beg, endv, dinv, b2, x);
  // classifier
  k_classifier<<<(NN + 49) / 50, 256, 0, stream>>>(x, Wc, bc, outc);
}

// Round 12
// 391.683 us; speedup vs baseline: 1.9474x; 1.1036x over previous
//
#include <hip/hip_runtime.h>

#define NN 100000
#define NE 1600000
#define D 128
#define ODIM 40
#define CHUNK 8192
#define NBUCK 196      // ceil(NN/512)
#define BCAP 10240     // bucket capacity (mean 8192, sigma~90 -> +22 sigma)

typedef unsigned int uint;
typedef unsigned short ushort;
typedef __attribute__((ext_vector_type(8))) short short8v;   // 8 bf16 = 4 VGPR MFMA frag
typedef __attribute__((ext_vector_type(4))) float f32x4;     // MFMA accumulator

// bf16 helpers (RNE)
__device__ __forceinline__ ushort bf16_rne(float x) {
  uint u = __float_as_uint(x);
  u = (u + 0x7FFFu + ((u >> 16) & 1u)) >> 16;
  return (ushort)u;
}
__device__ __forceinline__ float bf_lo(uint u) { return __uint_as_float(u << 16); }
__device__ __forceinline__ float bf_hi(uint u) { return __uint_as_float(u & 0xFFFF0000u); }

// ---------------- zero (bucketFill) ----------------
__global__ void k_zero(int* __restrict__ p, int n) {
  int i = blockIdx.x * blockDim.x + threadIdx.x;
  if (i < n) p[i] = 0;
}

// ---- pass A: bin edges into 196 fixed-capacity dst-bucket regions ----
// 512 thr x 196 blocks (CHUNK=8192): occupancy fix vs round-11's 98x256 (3.9% occ).
__global__ __launch_bounds__(512) void k_bin(const int* __restrict__ src,
    const int* __restrict__ dst, int* __restrict__ bucketFill, uint2* __restrict__ ebuf) {
  __shared__ int hist[NBUCK];
  __shared__ int hist2[NBUCK];
  __shared__ int gb[NBUCK];
  int tid = threadIdx.x;
  int base = blockIdx.x * CHUNK;
  int n = NE - base;
  if (n > CHUNK) n = CHUNK;
  for (int i = tid; i < NBUCK; i += 512) { hist[i] = 0; hist2[i] = 0; }
  __syncthreads();
  for (int i = tid; i < n; i += 512) {
    int d = dst[base + i];
    atomicAdd(&hist[d >> 9], 1);
  }
  __syncthreads();
  for (int i = tid; i < NBUCK; i += 512) {
    int cnt = hist[i];
    int off = (cnt > 0) ? atomicAdd(&bucketFill[i], cnt) : 0;
    gb[i] = i * BCAP + off;
  }
  __syncthreads();
  for (int i = tid; i < n; i += 512) {
    int s = src[base + i];
    int d = dst[base + i];
    int b = d >> 9;
    int lp = atomicAdd(&hist2[b], 1);
    int slot = gb[b] + lp;
    if (slot < (b + 1) * BCAP)            // overflow guard (statistically unreachable)
      ebuf[slot] = make_uint2((uint)s, (uint)d);
  }
}

// ---- pass B: per-bucket count + scan + CSR fill in LDS; writes csr/beg/end/dinv ----
// 512 threads: one thread per node of the bucket; halved serial passes.
__global__ __launch_bounds__(512) void k_fillb(const uint2* __restrict__ ebuf,
    const int* __restrict__ bucketFill, int* __restrict__ csr,
    int* __restrict__ beg, int* __restrict__ endv, float* __restrict__ dinv) {
  __shared__ int lfill[512];
  __shared__ int lfill2[512];
  __shared__ int loff[512];
  __shared__ int limage[BCAP];
  int tid = threadIdx.x;
  int b = blockIdx.x;
  int nb0 = b << 9;
  int nnodes = NN - nb0; if (nnodes > 512) nnodes = 512;
  int bn = bucketFill[b]; if (bn > BCAP) bn = BCAP;
  lfill[tid] = 0;
  lfill2[tid] = 0;
  __syncthreads();
  const uint2* eb = ebuf + b * BCAP;
  for (int i = tid; i < bn; i += 512) atomicAdd(&lfill[(int)eb[i].y - nb0], 1);
  __syncthreads();
  // inclusive Hillis-Steele scan over 512, one element per thread
  int v = lfill[tid];
  loff[tid] = v;
  __syncthreads();
  for (int off = 1; off < 512; off <<= 1) {
    int add = (tid >= off) ? loff[tid - off] : 0;
    __syncthreads();
    loff[tid] += add;
    __syncthreads();
  }
  int ex = loff[tid] - v;   // exclusive prefix
  __syncthreads();
  loff[tid] = ex;
  // per-node outputs (thread tid = node nb0+tid)
  if (tid < nnodes) {
    dinv[nb0 + tid] = rsqrtf((float)(v + 1));
    int bg = b * BCAP + ex;
    beg[nb0 + tid] = bg;
    endv[nb0 + tid] = bg + v;
  }
  __syncthreads();
  // place into LDS image
  for (int i = tid; i < bn; i += 512) {
    uint2 p = eb[i];
    int dl = (int)p.y - nb0;
    int lp = atomicAdd(&lfill2[dl], 1);
    limage[loff[dl] + lp] = (int)p.x;
  }
  __syncthreads();
  // coalesced write-out
  for (int i = tid; i < bn; i += 512) csr[b * BCAP + i] = limage[i];
}

// ---- MFMA GEMM: H[N,128] = bf16( dinv[n] * (X[N,128] @ W[128,128]) ) ----
// (verified round 11: absmax 3.9e-3) Block 64 nodes, 4 waves; C/D col=lane&15, row=(lane>>4)*4+reg.
__global__ __launch_bounds__(256) void k_gemm_mfma(const float* __restrict__ X,
    const float* __restrict__ W, const float* __restrict__ dinv, ushort* __restrict__ H) {
  __shared__ __align__(16) ushort Xb[64][136];   // 272B row = 4-bank shift (conflict floor)
  __shared__ __align__(16) ushort Wt[128][136];  // W transposed [feat][k]
  __shared__ float ddi[64];
  int tid = threadIdx.x;
  int nbase = blockIdx.x * 64;
  for (int i = tid; i < 64 * 128; i += 256) {
    int n = i >> 7, k = i & 127;
    int gn = nbase + n; if (gn >= NN) gn = NN - 1;
    Xb[n][k] = bf16_rne(X[gn * D + k]);
  }
  for (int i = tid; i < 128 * 128; i += 256) {
    int k = i >> 7, f = i & 127;
    Wt[f][k] = bf16_rne(W[i]);
  }
  if (tid < 64) {
    int gn = nbase + tid; if (gn >= NN) gn = NN - 1;
    ddi[tid] = dinv[gn];
  }
  __syncthreads();
  int w = tid >> 6, l = tid & 63;
  int lr = l & 15, lg = l >> 4;
  int n0 = w * 16;
  f32x4 acc[8];
#pragma unroll
  for (int t = 0; t < 8; t++) acc[t] = (f32x4){0.f, 0.f, 0.f, 0.f};
#pragma unroll
  for (int k0 = 0; k0 < 128; k0 += 32) {
    short8v a = *(const short8v*)&Xb[n0 + lr][k0 + lg * 8];
#pragma unroll
    for (int ft = 0; ft < 8; ft++) {
      short8v b = *(const short8v*)&Wt[ft * 16 + lr][k0 + lg * 8];
      acc[ft] = __builtin_amdgcn_mfma_f32_16x16x32_bf16(a, b, acc[ft], 0, 0, 0);
    }
  }
#pragma unroll
  for (int j = 0; j < 4; j++) {
    int nl = n0 + lg * 4 + j;
    int gn = nbase + nl;
    if (gn < NN) {
      float di = ddi[nl];
#pragma unroll
      for (int ft = 0; ft < 8; ft++) {
        H[gn * D + ft * 16 + lr] = bf16_rne(acc[ft][j] * di);
      }
    }
  }
}

// ---- aggregate: x = relu( dinv[i] * (Sum h'[s] + h'[i]) + b ), h' = dinv*h in bf16 ----
// wave = 1 node full row; 16 gathers in flight (latency hiding), 8 acc pairs.
__global__ __launch_bounds__(256) void k_aggregate(const ushort* __restrict__ h,
    const int* __restrict__ csr, const int* __restrict__ beg, const int* __restrict__ endv,
    const float* __restrict__ dinv, const float* __restrict__ bias,
    float* __restrict__ out) {
  int node = blockIdx.x * 4 + (threadIdx.x >> 6);
  int lane = threadIdx.x & 63;
  if (node >= NN) return;
  int e = beg[node];
  int end = endv[node];
  const uint* hv = (const uint*)h;   // one uint = 2 bf16 features; row = 64 uints
  float ax0 = 0.f, ax1 = 0.f, ax2 = 0.f, ax3 = 0.f;
  float ax4 = 0.f, ax5 = 0.f, ax6 = 0.f, ax7 = 0.f;
  float ay0 = 0.f, ay1 = 0.f, ay2 = 0.f, ay3 = 0.f;
  float ay4 = 0.f, ay5 = 0.f, ay6 = 0.f, ay7 = 0.f;
  for (; e + 15 < end; e += 16) {
    int s0 = csr[e],      s1 = csr[e + 1],  s2 = csr[e + 2],  s3 = csr[e + 3];
    int s4 = csr[e + 4],  s5 = csr[e + 5],  s6 = csr[e + 6],  s7 = csr[e + 7];
    int s8 = csr[e + 8],  s9 = csr[e + 9],  sa = csr[e + 10], sb = csr[e + 11];
    int sc = csr[e + 12], sd = csr[e + 13], se = csr[e + 14], sf = csr[e + 15];
    uint u0 = hv[s0 * 64 + lane], u1 = hv[s1 * 64 + lane];
    uint u2 = hv[s2 * 64 + lane], u3 = hv[s3 * 64 + lane];
    uint u4 = hv[s4 * 64 + lane], u5 = hv[s5 * 64 + lane];
    uint u6 = hv[s6 * 64 + lane], u7 = hv[s7 * 64 + lane];
    uint u8 = hv[s8 * 64 + lane], u9 = hv[s9 * 64 + lane];
    uint ua = hv[sa * 64 + lane], ub = hv[sb * 64 + lane];
    uint uc = hv[sc * 64 + lane], ud = hv[sd * 64 + lane];
    uint ue = hv[se * 64 + lane], uf = hv[sf * 64 + lane];
    ax0 += bf_lo(u0) + bf_lo(u8); ay0 += bf_hi(u0) + bf_hi(u8);
    ax1 += bf_lo(u1) + bf_lo(u9); ay1 += bf_hi(u1) + bf_hi(u9);
    ax2 += bf_lo(u2) + bf_lo(ua); ay2 += bf_hi(u2) + bf_hi(ua);
    ax3 += bf_lo(u3) + bf_lo(ub); ay3 += bf_hi(u3) + bf_hi(ub);
    ax4 += bf_lo(u4) + bf_lo(uc); ay4 += bf_hi(u4) + bf_hi(uc);
    ax5 += bf_lo(u5) + bf_lo(ud); ay5 += bf_hi(u5) + bf_hi(ud);
    ax6 += bf_lo(u6) + bf_lo(ue); ay6 += bf_hi(u6) + bf_hi(ue);
    ax7 += bf_lo(u7) + bf_lo(uf); ay7 += bf_hi(u7) + bf_hi(uf);
  }
  for (; e + 3 < end; e += 4) {
    int s0 = csr[e], s1 = csr[e + 1], s2 = csr[e + 2], s3 = csr[e + 3];
    uint u0 = hv[s0 * 64 + lane];
    uint u1 = hv[s1 * 64 + lane];
    uint u2 = hv[s2 * 64 + lane];
    uint u3 = hv[s3 * 64 + lane];
    ax0 += bf_lo(u0); ay0 += bf_hi(u0);
    ax1 += bf_lo(u1); ay1 += bf_hi(u1);
    ax2 += bf_lo(u2); ay2 += bf_hi(u2);
    ax3 += bf_lo(u3); ay3 += bf_hi(u3);
  }
  for (; e < end; e++) {
    int s0 = csr[e];
    uint u0 = hv[s0 * 64 + lane];
    ax0 += bf_lo(u0); ay0 += bf_hi(u0);
  }
  float di = dinv[node];
  uint us = hv[node * 64 + lane];
  float2 b = *(const float2*)&bias[lane * 2];
  float sx = ((ax0 + ax1) + (ax2 + ax3)) + ((ax4 + ax5) + (ax6 + ax7)) + bf_lo(us);
  float sy = ((ay0 + ay1) + (ay2 + ay3)) + ((ay4 + ay5) + (ay6 + ay7)) + bf_hi(us);
  float o0 = fmaxf(fmaf(di, sx, b.x), 0.f);
  float o1 = fmaxf(fmaf(di, sy, b.y), 0.f);
  float2 o = {o0, o1};
  *(float2*)&out[node * D + lane * 2] = o;
}

// ---------------- classifier: out[N,40] = X[N,128] @ Wc[128,40] + bc ----------------
__global__ __launch_bounds__(256) void k_classifier(const float* __restrict__ X,
    const float* __restrict__ Wc, const float* __restrict__ bc, float* __restrict__ out) {
  __shared__ __align__(16) float wl[D * ODIM];   // 20 KB
  __shared__ __align__(16) float xl[50 * D];     // 25 KB
  int tid = threadIdx.x;
  for (int i = tid; i < D * ODIM; i += 256) wl[i] = Wc[i];
  int nbase = blockIdx.x * 50;
  for (int i = tid; i < 50 * D; i += 256) {
    int gn = nbase + (i >> 7);
    xl[i] = (gn < NN) ? X[gn * D + (i & 127)] : 0.f;
  }
  __syncthreads();
  int fg = tid % 10;   // feature group of 4
  int np = tid / 10;   // node pair
  if (np < 25) {
    float acc0[4] = {0, 0, 0, 0};
    float acc1[4] = {0, 0, 0, 0};
    const float* x0 = &xl[(np * 2) * D];
    const float* x1 = &xl[(np * 2 + 1) * D];
#pragma unroll 4
    for (int k = 0; k < D; k++) {
      float4 w = *(float4*)&wl[k * ODIM + fg * 4];
      float xv0 = x0[k];
      float xv1 = x1[k];
      acc0[0] = fmaf(xv0, w.x, acc0[0]); acc0[1] = fmaf(xv0, w.y, acc0[1]);
      acc0[2] = fmaf(xv0, w.z, acc0[2]); acc0[3] = fmaf(xv0, w.w, acc0[3]);
      acc1[0] = fmaf(xv1, w.x, acc1[0]); acc1[1] = fmaf(xv1, w.y, acc1[1]);
      acc1[2] = fmaf(xv1, w.z, acc1[2]); acc1[3] = fmaf(xv1, w.w, acc1[3]);
    }
    float4 b = *(const float4*)&bc[fg * 4];
    int gn0 = nbase + np * 2;
    int gn1 = gn0 + 1;
    if (gn0 < NN) {
      float4 o = {acc0[0] + b.x, acc0[1] + b.y, acc0[2] + b.z, acc0[3] + b.w};
      *(float4*)&out[gn0 * ODIM + fg * 4] = o;
    }
    if (gn1 < NN) {
      float4 o = {acc1[0] + b.x, acc1[1] + b.y, acc1[2] + b.z, acc1[3] + b.w};
      *(float4*)&out[gn1 * ODIM + fg * 4] = o;
    }
  }
}

extern "C" void kernel_launch(void* const* d_in, const int* in_sizes, int n_in,
                              void* d_out, int out_size, void* d_ws, size_t ws_size,
                              hipStream_t stream) {
  const float* fts = (const float*)d_in[0];
  const int*   ei  = (const int*)d_in[1];
  const float* W1  = (const float*)d_in[2];
  const float* b1  = (const float*)d_in[3];
  const float* W2  = (const float*)d_in[4];
  const float* b2  = (const float*)d_in[5];
  const float* Wc  = (const float*)d_in[6];
  const float* bc  = (const float*)d_in[7];
  const int* src = ei;        // edge_index[0]
  const int* dst = ei + NE;   // edge_index[1]

  // workspace layout (16B-aligned offsets)
  char* ws = (char*)d_ws;
  int*    bucketFill = (int*)(ws + 0);              // 1024 B
  int*    beg        = (int*)(ws + 1024);           // 400000 B
  int*    endv       = (int*)(ws + 401024);         // 400000 B
  float*  dinv       = (float*)(ws + 801024);       // 400000 B
  int*    csr        = (int*)(ws + 1201024);        // 196*10240*4 = 8028160 B
  uint2*  ebuf       = (uint2*)(ws + 9229184);      // 196*10240*8 = 16056320 B
  ushort* h          = (ushort*)(ws + 25285504);    // 25600000 B (bf16, row-major)
  // total ~50.9 MB

  float* outc = (float*)d_out;              // [N,40]
  float* x    = (float*)d_out + NN * ODIM;  // [N,128]  (x1 lives here, overwritten by x2)

  k_zero<<<1, 256, 0, stream>>>(bucketFill, NBUCK);
  k_bin<<<(NE + CHUNK - 1) / CHUNK, 512, 0, stream>>>(src, dst, bucketFill, ebuf);
  k_fillb<<<NBUCK, 512, 0, stream>>>(ebuf, bucketFill, csr, beg, endv, dinv);

  // layer 1: h = bf16(dinv * (fts @ W1)) ; x1 = relu(dinv*(sum+self) + b1)
  k_gemm_mfma<<<(NN + 63) / 64, 256, 0, stream>>>(fts, W1, dinv, h);
  k_aggregate<<<(NN + 3) / 4, 256, 0, stream>>>(h, csr, beg, endv, dinv, b1, x);
  // layer 2
  k_gemm_mfma<<<(NN + 63) / 64, 256, 0, stream>>>(x, W2, dinv, h);
  k_aggregate<<<(NN + 3) / 4, 256, 0, stream>>>(h, csr, beg, endv, dinv, b2, x);
  // classifier
  k_classifier<<<(NN + 49) / 50, 256, 0, stream>>>(x, Wc, bc, outc);
}